// Round 1
// baseline (120.854 us; speedup 1.0000x reference)
//
#include <hip/hip_runtime.h>
#include <hip/hip_bf16.h>

#define N_NODES 25000
#define KFAN    32
#define FIN     256
#define FOUT    256

typedef float  f32x4  __attribute__((ext_vector_type(4)));
typedef short  s16x8  __attribute__((ext_vector_type(8)));

// round-to-nearest-even fp32 -> bf16 bits (scalar path, transpose kernel)
__device__ __forceinline__ ushort f2bf(float f) {
    unsigned int u = __float_as_uint(f);
    u += 0x7fffu + ((u >> 16) & 1u);
    return (ushort)(u >> 16);
}

// packed RNE conversion: lo = bf16(a), hi = bf16(b) in one instruction
__device__ __forceinline__ unsigned int pack2(float a, float b) {
    unsigned int r;
    asm("v_cvt_pk_bf16_f32 %0, %1, %2" : "=v"(r) : "v"(a), "v"(b));
    return r;
}

// ---------------- Kernel 0: Wt[n][k] = bf16(W[k][n])  (256x256) ------------
__global__ __launch_bounds__(256) void transpose_w(
    const float* __restrict__ W, ushort* __restrict__ Wt)
{
    __shared__ float ls[32][33];
    const int bid = blockIdx.x;        // 64 blocks
    const int kt  = bid & 7;           // k-tile
    const int nt  = bid >> 3;          // n-tile
    const int t   = threadIdx.x;

    {
        int kl = t >> 3, n4 = (t & 7) * 4;
        float4 v = *(const float4*)(W + (size_t)(kt * 32 + kl) * FOUT + nt * 32 + n4);
        ls[kl][n4 + 0] = v.x; ls[kl][n4 + 1] = v.y;
        ls[kl][n4 + 2] = v.z; ls[kl][n4 + 3] = v.w;
    }
    __syncthreads();
    {
        int nl = t >> 3, k4 = (t & 7) * 4;
        ushort4 o;
        o.x = f2bf(ls[k4 + 0][nl]);
        o.y = f2bf(ls[k4 + 1][nl]);
        o.z = f2bf(ls[k4 + 2][nl]);
        o.w = f2bf(ls[k4 + 3][nl]);
        *(ushort4*)(Wt + (size_t)(nt * 32 + nl) * FIN + kt * 32 + k4) = o;
    }
}

// ---------------- Kernel 1: y = relu(x @ W + b) via MFMA bf16 --------------
// Tile M=64 x N=128; block 256 thr (4 waves); wave wv owns 32 cols.
// FULL-K staging: one 64x256 bf16 tile in LDS, 2 barriers per block total
// (was 8).  Packing via v_cvt_pk_bf16_f32 (1 inst / 2 values).
// Block swizzle pairs the two col-halves of the same rows on the SAME XCD
// (ids differ by 8 under round-robin dispatch) so x rows are fetched once
// per XCD.
__global__ __launch_bounds__(256, 4) void gemm_mfma(
    const float*  __restrict__ x,     // [N][FIN] fp32
    const ushort* __restrict__ Wt,    // [FOUT][FIN] bf16 bits (W^T)
    const float*  __restrict__ bias,  // [FOUT]
    ushort*       __restrict__ y)     // [N][FOUT] bf16 bits
{
    __shared__ ushort As[64][264];    // 33.8 KB; row stride 528B (132 dw ≡ 4 mod 32)

    const int tid  = threadIdx.x;
    const int lane = tid & 63;
    const int wv   = tid >> 6;
    const int l16  = lane & 15;
    const int q    = lane >> 4;       // quad 0..3

    // swizzle: b = 16m + 8c + j  ->  rb = 8m + j, cb = c  (pairs 8 apart -> same XCD)
    const int b = blockIdx.x;         // 782 blocks
    int rb, cb;
    if (b < 768) { rb = ((b >> 4) << 3) + (b & 7); cb = (b >> 3) & 1; }
    else         { const int t2 = b - 768; rb = 384 + (t2 >> 1); cb = t2 & 1; }
    const int row0 = rb * 64;
    const int n0   = cb * 128 + wv * 32;

    // ---- stage full K: thread t -> row (t>>2), 64 k at (t&3)*64 ----
    {
        const int r     = tid >> 2;
        const int kbase = (tid & 3) * 64;
        int gr = row0 + r;
        if (gr >= N_NODES) gr = N_NODES - 1;   // clamp: rows >=N computed, never stored
        const float* p = x + (size_t)gr * FIN + kbase;
        float4 v[16];
        #pragma unroll
        for (int i = 0; i < 16; ++i) v[i] = *(const float4*)(p + i * 4);
        #pragma unroll
        for (int i = 0; i < 8; ++i) {
            uint4 pk;
            pk.x = pack2(v[2*i].x,     v[2*i].y);
            pk.y = pack2(v[2*i].z,     v[2*i].w);
            pk.z = pack2(v[2*i+1].x,   v[2*i+1].y);
            pk.w = pack2(v[2*i+1].z,   v[2*i+1].w);
            *(uint4*)&As[r][kbase + i * 8] = pk;
        }
    }
    __syncthreads();

    f32x4 acc[4][2];
    #pragma unroll
    for (int i = 0; i < 4; ++i)
        #pragma unroll
        for (int j = 0; j < 2; ++j) acc[i][j] = (f32x4)0.f;

    const ushort* wp0 = Wt + (size_t)(n0 + l16) * FIN;
    const ushort* wp1 = wp0 + (size_t)16 * FIN;

    #pragma unroll
    for (int kk = 0; kk < FIN; kk += 32) {
        const int k0 = kk + q * 8;
        s16x8 a[4], bfr[2];
        bfr[0] = *(const s16x8*)(wp0 + k0);
        bfr[1] = *(const s16x8*)(wp1 + k0);
        #pragma unroll
        for (int mt = 0; mt < 4; ++mt)
            a[mt] = *(const s16x8*)&As[mt * 16 + l16][k0];
        #pragma unroll
        for (int mt = 0; mt < 4; ++mt)
            #pragma unroll
            for (int ct = 0; ct < 2; ++ct)
                acc[mt][ct] = __builtin_amdgcn_mfma_f32_16x16x32_bf16(a[mt], bfr[ct], acc[mt][ct], 0, 0, 0);
    }

    // epilogue: +bias, relu, bf16 store.  D layout: col=lane&15, row=q*4+reg
    #pragma unroll
    for (int ct = 0; ct < 2; ++ct) {
        const int col = n0 + ct * 16 + l16;
        const float bv = bias[col];
        #pragma unroll
        for (int mt = 0; mt < 4; ++mt) {
            #pragma unroll
            for (int rr = 0; rr < 4; ++rr) {
                int row = row0 + mt * 16 + q * 4 + rr;
                if (row < N_NODES)
                    y[(size_t)row * FOUT + col] = f2bf(fmaxf(acc[mt][ct][rr] + bv, 0.f));
            }
        }
    }
}

// ---------------- Kernel 2: out[n][o] = max_k y[neigh[n][k]][o] ------------
// 64-col chunks pinned per-XCD (y slice 3.2MB < 4MB L2), 16B gather loads:
// 8 lanes per node-group, 8 nodes per wave, 32 nodes per block.
// Index distribution via a 4.6KB LDS tile + ds_read_b128 (8 reads/thread,
// same-address broadcast within a group) instead of 32 ds_bpermute.
// Packed i16-max on bf16 bits (valid: relu => y >= 0); dual accumulators
// halve the dependency chain.
__global__ __launch_bounds__(256) void pool_max(
    const ushort* __restrict__ y,     // [N][FOUT] bf16 bits
    const int*    __restrict__ neigh, // [N][KFAN]
    float*        __restrict__ out)   // [N][FOUT] fp32
{
    __shared__ int nidx[32][36];      // stride 36 ints: 16B aligned rows, banks spread

    const int bid   = blockIdx.x;
    const int chunk = bid & 3;        // 64-col chunk, XCD-affine under %8 RR
    const int nb    = bid >> 2;
    const int tid   = threadIdx.x;

    {   // stage 32 nodes x 32 indices (coalesced 4KB)
        const int nl = tid >> 3, k4 = (tid & 7) * 4;
        int gn = nb * 32 + nl;
        if (gn >= N_NODES) gn = N_NODES - 1;
        *(int4*)&nidx[nl][k4] = *(const int4*)(neigh + (size_t)gn * KFAN + k4);
    }
    __syncthreads();

    const int lane   = tid & 63;
    const int g      = lane >> 3;     // node-group within wave (0..7)
    const int gl     = lane & 7;      // lane within group
    const int wv     = tid >> 6;
    const int node_l = wv * 8 + g;
    const int n      = nb * 32 + node_l;

    const ushort* yc = y + chunk * 64 + gl * 8;

    s16x8 acc0 = (s16x8)0, acc1 = (s16x8)0;
    #pragma unroll
    for (int k = 0; k < KFAN; k += 4) {
        const int4 ii = *(const int4*)&nidx[node_l][k];
        s16x8 c0 = *(const s16x8*)(yc + (size_t)ii.x * FOUT);
        s16x8 c1 = *(const s16x8*)(yc + (size_t)ii.y * FOUT);
        s16x8 c2 = *(const s16x8*)(yc + (size_t)ii.z * FOUT);
        s16x8 c3 = *(const s16x8*)(yc + (size_t)ii.w * FOUT);
        acc0 = __builtin_elementwise_max(acc0, c0);
        acc1 = __builtin_elementwise_max(acc1, c1);
        acc0 = __builtin_elementwise_max(acc0, c2);
        acc1 = __builtin_elementwise_max(acc1, c3);
    }
    acc0 = __builtin_elementwise_max(acc0, acc1);

    if (n < N_NODES) {
        f32x4 o0, o1;
        o0.x = __uint_as_float(((unsigned int)(ushort)acc0[0]) << 16);
        o0.y = __uint_as_float(((unsigned int)(ushort)acc0[1]) << 16);
        o0.z = __uint_as_float(((unsigned int)(ushort)acc0[2]) << 16);
        o0.w = __uint_as_float(((unsigned int)(ushort)acc0[3]) << 16);
        o1.x = __uint_as_float(((unsigned int)(ushort)acc0[4]) << 16);
        o1.y = __uint_as_float(((unsigned int)(ushort)acc0[5]) << 16);
        o1.z = __uint_as_float(((unsigned int)(ushort)acc0[6]) << 16);
        o1.w = __uint_as_float(((unsigned int)(ushort)acc0[7]) << 16);
        float* op = out + (size_t)n * FOUT + chunk * 64 + gl * 8;
        __builtin_nontemporal_store(o0, (f32x4*)op);
        __builtin_nontemporal_store(o1, (f32x4*)(op + 4));
    }
}

extern "C" void kernel_launch(void* const* d_in, const int* in_sizes, int n_in,
                              void* d_out, int out_size, void* d_ws, size_t ws_size,
                              hipStream_t stream) {
    const float* x     = (const float*)d_in[0];
    const int*   neigh = (const int*)  d_in[1];
    const float* W     = (const float*)d_in[2];
    const float* bias  = (const float*)d_in[3];
    float*       out   = (float*)d_out;
    ushort*      y     = (ushort*)d_ws;    // 12.8 MB of the 256 MiB ws
    // Park W^T (bf16, 128KB) at the front of d_out: gemm reads it, then
    // pool_max fully overwrites d_out afterwards (stream-ordered).
    ushort*      Wt    = (ushort*)d_out;

    transpose_w<<<64, 256, 0, stream>>>(W, Wt);

    gemm_mfma<<<782, 256, 0, stream>>>(x, Wt, bias, y);

    const int nblocks = ((N_NODES + 31) / 32) * 4;         // 782*4 = 3128
    pool_max<<<nblocks, 256, 0, stream>>>(y, neigh, out);
}